// Round 12
// baseline (218.627 us; speedup 1.0000x reference)
//
#include <hip/hip_runtime.h>
#include <math.h>

#define BB 2
#define TT 4096
#define CC 64
#define HH 4
#define DH 16
#define NROW (BB*TT)                 // 8192
#define NBLK 512
#define SCALE 0.36067376022224085f   // 0.25 * log2(e)

typedef __fp16 h4 __attribute__((ext_vector_type(4)));
typedef __fp16 h2 __attribute__((ext_vector_type(2)));
typedef float  f4 __attribute__((ext_vector_type(4)));

union U32B { struct { uint4 a, b; } u; h4 f[4]; };
__device__ __forceinline__ U32B ld32(const __fp16* p) {
    U32B r;
    r.u.a = *(const uint4*)p;
    r.u.b = *(const uint4*)(p + 8);
    return r;
}

__device__ __forceinline__ void grid_barrier(unsigned* cnt) {
    __syncthreads();
    if (threadIdx.x == 0) {
        __threadfence();                       // release our phase's writes (device scope)
        __hip_atomic_fetch_add(cnt, 1u, __ATOMIC_RELEASE, __HIP_MEMORY_SCOPE_AGENT);
        while (__hip_atomic_load(cnt, __ATOMIC_ACQUIRE, __HIP_MEMORY_SCOPE_AGENT) < (unsigned)NBLK)
            __builtin_amdgcn_s_sleep(2);
    }
    __syncthreads();
}

// Fused: phase1 qkv GEMM -> swizzled Q,K,V | barrier | phase2 flash attn | barrier | phase3 proj
// 512 blocks x 256 thr.
__global__ __launch_bounds__(256) void fused_kernel(const float* __restrict__ x,
        const float* __restrict__ w_attn, const float* __restrict__ b_attn,
        const float* __restrict__ w_proj, const float* __restrict__ b_proj,
        __fp16* __restrict__ Q, __fp16* __restrict__ K, __fp16* __restrict__ VT,
        __fp16* __restrict__ yh, float* __restrict__ out, unsigned* __restrict__ bar) {
    __shared__ __align__(16) char smraw[20480];
    const int t = threadIdx.x;
    const int bid = blockIdx.x;
    const int wave = t >> 6, lane = t & 63;
    const int lq = lane & 15, g = lane >> 4;

    // ================= Phase 1: qkv (block = 16 rows; wave w -> tiles w*3..w*3+2) =================
    {
        __fp16 (*smv)[16] = (__fp16(*)[16])smraw;   // [h*16+d][t-col]
        const int r0 = bid*16;
        const int b = r0 >> 12, tt0 = r0 & (TT-1);
        const int chunk = tt0 >> 6, seg = (tt0 >> 4) & 3;

        h4 xb[4];
        const float* xrow = x + (size_t)(r0 + lq)*CC;
        #pragma unroll
        for (int s = 0; s < 4; s++) {
            float4 xv = *(const float4*)(xrow + s*16 + g*4);
            h2 lo = __builtin_amdgcn_cvt_pkrtz(xv.x, xv.y);
            h2 hi = __builtin_amdgcn_cvt_pkrtz(xv.z, xv.w);
            xb[s] = (h4){lo.x, lo.y, hi.x, hi.y};
        }

        #pragma unroll
        for (int j = 0; j < 3; j++) {
            const int nt = wave*3 + j;
            const int o0 = nt*16;
            const float sc = (nt < 4) ? SCALE : 1.0f;
            float4 bv = *(const float4*)(b_attn + o0 + g*4);
            f4 acc = {bv.x*sc, bv.y*sc, bv.z*sc, bv.w*sc};
            #pragma unroll
            for (int s = 0; s < 4; s++) {
                float4 wv = *(const float4*)(w_attn + (size_t)(o0 + lq)*CC + s*16 + g*4);
                h2 lo = __builtin_amdgcn_cvt_pkrtz(wv.x*sc, wv.y*sc);
                h2 hi = __builtin_amdgcn_cvt_pkrtz(wv.z*sc, wv.w*sc);
                h4 af = (h4){lo.x, lo.y, hi.x, hi.y};
                acc = __builtin_amdgcn_mfma_f32_16x16x16f16(af, xb[s], acc, 0, 0, 0);
            }
            h2 plo = __builtin_amdgcn_cvt_pkrtz(acc.x, acc.y);
            h2 phi = __builtin_amdgcn_cvt_pkrtz(acc.z, acc.w);
            h4 pk = (h4){plo.x, plo.y, phi.x, phi.y};
            if (nt < 8) {
                const int part = nt >> 2, h = nt & 3;
                __fp16* dst = ((part == 0) ? Q : K)
                    + (size_t)(b*HH + h)*(TT*DH) + chunk*1024 + lane*16 + seg*4;
                *(h4*)dst = pk;
            } else {
                const int h = nt - 8;
                smv[h*16 + g*4 + 0][lq] = pk.x;
                smv[h*16 + g*4 + 1][lq] = pk.y;
                smv[h*16 + g*4 + 2][lq] = pk.z;
                smv[h*16 + g*4 + 3][lq] = pk.w;
            }
        }
        __syncthreads();
        {
            const int h = t >> 6, n = t & 63;
            h4 vv = *(const h4*)&smv[h*16 + (n & 15)][(n >> 4)*4];
            __fp16* dst = VT + (size_t)(b*HH + h)*(TT*DH) + chunk*1024 + n*16 + seg*4;
            *(h4*)dst = vv;
        }
    }

    grid_barrier(&bar[0]);

    // ================= Phase 2: flash attention (block = (head, 64-q tile); wave = ksplit) =================
    {
        f4    (*Osm)[4][64] = (f4(*)[4][64])smraw;                 // 16 KB
        float (*Lsm)[4][64] = (float(*)[4][64])(smraw + 16384);    // 4 KB
        const int head = bid >> 6;
        const int qt   = bid & 63;
        const int q0 = qt*64;
        const __fp16* Qh = Q  + (size_t)head*TT*DH;
        const __fp16* Kh = K  + (size_t)head*TT*DH;
        const __fp16* Vh = VT + (size_t)head*TT*DH;

        U32B qfu = ld32(Qh + (size_t)qt*1024 + lane*16);

        f4 O[4];
        float lp[4];
        #pragma unroll
        for (int h = 0; h < 4; h++) { O[h] = (f4){0.f,0.f,0.f,0.f}; lp[h] = 0.f; }

        const __fp16* kbase = Kh + (size_t)(wave*16)*1024 + lane*16;
        const __fp16* vbase = Vh + (size_t)(wave*16)*1024 + lane*16;

        U32B ka = ld32(kbase), va = ld32(vbase);
        U32B kb, vb;

#define ATTN_CHUNK(KF, VF)                                                        \
    {                                                                             \
        const f4 z = {0.f, 0.f, 0.f, 0.f};                                        \
        _Pragma("unroll")                                                         \
        for (int h = 0; h < 4; h++) {                                             \
            f4 S0 = __builtin_amdgcn_mfma_f32_16x16x16f16(KF.f[0], qfu.f[h], z, 0,0,0);\
            f4 S1 = __builtin_amdgcn_mfma_f32_16x16x16f16(KF.f[1], qfu.f[h], z, 0,0,0);\
            f4 S2 = __builtin_amdgcn_mfma_f32_16x16x16f16(KF.f[2], qfu.f[h], z, 0,0,0);\
            f4 S3 = __builtin_amdgcn_mfma_f32_16x16x16f16(KF.f[3], qfu.f[h], z, 0,0,0);\
            float p0, p1, p2, p3; h2 lo, hi; h4 P; float lacc = 0.f;              \
            p0 = __builtin_amdgcn_exp2f(S0.x); p1 = __builtin_amdgcn_exp2f(S0.y); \
            p2 = __builtin_amdgcn_exp2f(S0.z); p3 = __builtin_amdgcn_exp2f(S0.w); \
            lacc += p0 + p1 + p2 + p3;                                            \
            lo = __builtin_amdgcn_cvt_pkrtz(p0, p1);                              \
            hi = __builtin_amdgcn_cvt_pkrtz(p2, p3);                              \
            P = (h4){lo.x, lo.y, hi.x, hi.y};                                     \
            O[h] = __builtin_amdgcn_mfma_f32_16x16x16f16(VF.f[0], P, O[h], 0,0,0);\
            p0 = __builtin_amdgcn_exp2f(S1.x); p1 = __builtin_amdgcn_exp2f(S1.y); \
            p2 = __builtin_amdgcn_exp2f(S1.z); p3 = __builtin_amdgcn_exp2f(S1.w); \
            lacc += p0 + p1 + p2 + p3;                                            \
            lo = __builtin_amdgcn_cvt_pkrtz(p0, p1);                              \
            hi = __builtin_amdgcn_cvt_pkrtz(p2, p3);                              \
            P = (h4){lo.x, lo.y, hi.x, hi.y};                                     \
            O[h] = __builtin_amdgcn_mfma_f32_16x16x16f16(VF.f[1], P, O[h], 0,0,0);\
            p0 = __builtin_amdgcn_exp2f(S2.x); p1 = __builtin_amdgcn_exp2f(S2.y); \
            p2 = __builtin_amdgcn_exp2f(S2.z); p3 = __builtin_amdgcn_exp2f(S2.w); \
            lacc += p0 + p1 + p2 + p3;                                            \
            lo = __builtin_amdgcn_cvt_pkrtz(p0, p1);                              \
            hi = __builtin_amdgcn_cvt_pkrtz(p2, p3);                              \
            P = (h4){lo.x, lo.y, hi.x, hi.y};                                     \
            O[h] = __builtin_amdgcn_mfma_f32_16x16x16f16(VF.f[2], P, O[h], 0,0,0);\
            p0 = __builtin_amdgcn_exp2f(S3.x); p1 = __builtin_amdgcn_exp2f(S3.y); \
            p2 = __builtin_amdgcn_exp2f(S3.z); p3 = __builtin_amdgcn_exp2f(S3.w); \
            lacc += p0 + p1 + p2 + p3;                                            \
            lo = __builtin_amdgcn_cvt_pkrtz(p0, p1);                              \
            hi = __builtin_amdgcn_cvt_pkrtz(p2, p3);                              \
            P = (h4){lo.x, lo.y, hi.x, hi.y};                                     \
            O[h] = __builtin_amdgcn_mfma_f32_16x16x16f16(VF.f[3], P, O[h], 0,0,0);\
            lp[h] += lacc;                                                        \
        }                                                                         \
    }

        for (int it = 0; it < 16; it += 2) {
            kb = ld32(kbase + (size_t)(it + 1)*1024);
            vb = ld32(vbase + (size_t)(it + 1)*1024);
            ATTN_CHUNK(ka, va)
            {
                const int c2 = (it + 2 < 16) ? it + 2 : 15;
                ka = ld32(kbase + (size_t)c2*1024);
                va = ld32(vbase + (size_t)c2*1024);
            }
            ATTN_CHUNK(kb, vb)
        }
#undef ATTN_CHUNK

        __syncthreads();   // smraw reuse safe: phase-1 done locally
        #pragma unroll
        for (int h = 0; h < 4; h++) {
            Osm[wave][h][lane] = O[h];
            Lsm[wave][h][lane] = lp[h];
        }
        __syncthreads();

        f4 Os = Osm[0][wave][lane];
        Os += Osm[1][wave][lane];
        Os += Osm[2][wave][lane];
        Os += Osm[3][wave][lane];
        float L = 0.f;
        #pragma unroll
        for (int ks = 0; ks < 4; ks++)
            #pragma unroll
            for (int gg = 0; gg < 4; gg++)
                L += Lsm[ks][wave][gg*16 + lq];
        const float rinv = 1.f / L;
        h2 lo = __builtin_amdgcn_cvt_pkrtz(Os.x*rinv, Os.y*rinv);
        h2 hi = __builtin_amdgcn_cvt_pkrtz(Os.z*rinv, Os.w*rinv);
        h4 pk = (h4){lo.x, lo.y, hi.x, hi.y};
        const int b = head >> 2, hh = head & 3;
        const size_t rblk = ((size_t)b*TT + q0) / 16 + wave;
        *(h4*)(yh + rblk*1024 + lane*16 + hh*4) = pk;
    }

    grid_barrier(&bar[1]);

    // ================= Phase 3: proj (block = 16 rows; wave w -> o-range w*16..) =================
    {
        const int r0 = bid*16;
        const int o0 = wave*16;

        U32B yb = ld32(yh + (size_t)bid*1024 + lane*16);

        float4 bv = *(const float4*)(b_proj + o0 + g*4);
        f4 acc = {bv.x, bv.y, bv.z, bv.w};
        #pragma unroll
        for (int s = 0; s < 4; s++) {
            float4 wv = *(const float4*)(w_proj + (size_t)(o0 + lq)*CC + s*16 + g*4);
            h2 lo = __builtin_amdgcn_cvt_pkrtz(wv.x, wv.y);
            h2 hi = __builtin_amdgcn_cvt_pkrtz(wv.z, wv.w);
            h4 af = (h4){lo.x, lo.y, hi.x, hi.y};
            acc = __builtin_amdgcn_mfma_f32_16x16x16f16(af, yb.f[s], acc, 0, 0, 0);
        }
        *(float4*)(out + (size_t)(r0 + lq)*CC + o0 + g*4) = (float4){acc.x, acc.y, acc.z, acc.w};
    }
}

extern "C" void kernel_launch(void* const* d_in, const int* in_sizes, int n_in,
                              void* d_out, int out_size, void* d_ws, size_t ws_size,
                              hipStream_t stream) {
    const float* x      = (const float*)d_in[0];
    const float* w_attn = (const float*)d_in[1];
    const float* b_attn = (const float*)d_in[2];
    const float* w_proj = (const float*)d_in[3];
    const float* b_proj = (const float*)d_in[4];
    float* out = (float*)d_out;

    const size_t headsz = (size_t)BB*HH*TT*DH;
    __fp16* Q   = (__fp16*)d_ws;
    __fp16* K   = Q + headsz;
    __fp16* VT  = K + headsz;
    __fp16* yh  = VT + headsz;
    unsigned* bar = (unsigned*)((char*)d_ws + (16u << 20));   // well past 4MB of buffers

    hipMemsetAsync(bar, 0, 16, stream);                       // graph-capture-safe memset node
    fused_kernel<<<NBLK, 256, 0, stream>>>(x, w_attn, b_attn, w_proj, b_proj,
                                           Q, K, VT, yh, out, bar);
}

// Round 13
// 96.255 us; speedup vs baseline: 2.2713x; 2.2713x over previous
//
#include <hip/hip_runtime.h>
#include <math.h>

#define BB 2
#define TT 4096
#define CC 64
#define HH 4
#define DH 16
#define NROW (BB*TT)                 // 8192
#define SCALE 0.36067376022224085f   // 0.25 * log2(e)

typedef __fp16 h4 __attribute__((ext_vector_type(4)));
typedef __fp16 h2 __attribute__((ext_vector_type(2)));
typedef float  f4 __attribute__((ext_vector_type(4)));

// Fragment-major swizzled layout, per (b,h), per 64-row chunk (see R11).
union U32B { struct { uint4 a, b; } u; h4 f[4]; };
__device__ __forceinline__ U32B ld32(const __fp16* p) {
    U32B r;
    r.u.a = *(const uint4*)p;
    r.u.b = *(const uint4*)(p + 8);
    return r;
}

// ---------------- Kernel A: qkv GEMM -> swizzled Q,K,V (identical to R11) ----------------
__global__ __launch_bounds__(256) void qkv_kernel(const float* __restrict__ x,
        const float* __restrict__ w, const float* __restrict__ bias,
        __fp16* __restrict__ Q, __fp16* __restrict__ K, __fp16* __restrict__ VT) {
    __shared__ __fp16 smv[64][16];
    const int t = threadIdx.x;
    const int wave = t >> 6, lane = t & 63;
    const int lq = lane & 15, g = lane >> 4;
    const int r0 = blockIdx.x*16;
    const int b = r0 >> 12, tt0 = r0 & (TT-1);
    const int chunk = tt0 >> 6, seg = (tt0 >> 4) & 3;

    h4 xb[4];
    const float* xrow = x + (size_t)(r0 + lq)*CC;
    #pragma unroll
    for (int s = 0; s < 4; s++) {
        float4 xv = *(const float4*)(xrow + s*16 + g*4);
        h2 lo = __builtin_amdgcn_cvt_pkrtz(xv.x, xv.y);
        h2 hi = __builtin_amdgcn_cvt_pkrtz(xv.z, xv.w);
        xb[s] = (h4){lo.x, lo.y, hi.x, hi.y};
    }

    #pragma unroll
    for (int j = 0; j < 3; j++) {
        const int nt = wave*3 + j;
        const int o0 = nt*16;
        const float sc = (nt < 4) ? SCALE : 1.0f;
        float4 bv = *(const float4*)(bias + o0 + g*4);
        f4 acc = {bv.x*sc, bv.y*sc, bv.z*sc, bv.w*sc};
        #pragma unroll
        for (int s = 0; s < 4; s++) {
            float4 wv = *(const float4*)(w + (size_t)(o0 + lq)*CC + s*16 + g*4);
            h2 lo = __builtin_amdgcn_cvt_pkrtz(wv.x*sc, wv.y*sc);
            h2 hi = __builtin_amdgcn_cvt_pkrtz(wv.z*sc, wv.w*sc);
            h4 af = (h4){lo.x, lo.y, hi.x, hi.y};
            acc = __builtin_amdgcn_mfma_f32_16x16x16f16(af, xb[s], acc, 0, 0, 0);
        }
        h2 plo = __builtin_amdgcn_cvt_pkrtz(acc.x, acc.y);
        h2 phi = __builtin_amdgcn_cvt_pkrtz(acc.z, acc.w);
        h4 pk = (h4){plo.x, plo.y, phi.x, phi.y};
        if (nt < 8) {
            const int part = nt >> 2, h = nt & 3;
            __fp16* dst = ((part == 0) ? Q : K)
                + (size_t)(b*HH + h)*(TT*DH) + chunk*1024 + lane*16 + seg*4;
            *(h4*)dst = pk;
        } else {
            const int h = nt - 8;
            smv[h*16 + g*4 + 0][lq] = pk.x;
            smv[h*16 + g*4 + 1][lq] = pk.y;
            smv[h*16 + g*4 + 2][lq] = pk.z;
            smv[h*16 + g*4 + 3][lq] = pk.w;
        }
    }
    __syncthreads();
    {
        const int h = t >> 6, n = t & 63;
        h4 vv = *(const h4*)&smv[h*16 + (n & 15)][(n >> 4)*4];
        __fp16* dst = VT + (size_t)(b*HH + h)*(TT*DH) + chunk*1024 + n*16 + seg*4;
        *(h4*)dst = vv;
    }
}

// ---------------- Kernel B: flash attention, 128 q-rows/wave, split-K x4, swizzled frags ----------------
// 256 blocks x 256 thr: block = (head, 128-row qtile); wave w = k-range [w*1024,(w+1)*1024)
__global__ __launch_bounds__(256) void attn_kernel(const __fp16* __restrict__ Q,
        const __fp16* __restrict__ K, const __fp16* __restrict__ VT,
        __fp16* __restrict__ yh) {
    __shared__ f4    Osm[4][8][64];   // [ksplit][qblk][lane]  32 KB
    __shared__ float Lsm[4][8][64];   // 8 KB
    const int t = threadIdx.x;
    const int wave = t >> 6, lane = t & 63;
    const int lq = lane & 15, g = lane >> 4;
    const int head = blockIdx.x >> 5;
    const int qt   = blockIdx.x & 31;
    const int q0 = qt*128;
    const __fp16* Qh = Q  + (size_t)head*TT*DH;
    const __fp16* Kh = K  + (size_t)head*TT*DH;
    const __fp16* Vh = VT + (size_t)head*TT*DH;

    // Q frags: 8 h-blocks from two 64-row chunks
    const U32B qa = ld32(Qh + (size_t)(qt*2    )*1024 + lane*16);
    const U32B qb = ld32(Qh + (size_t)(qt*2 + 1)*1024 + lane*16);

    f4 O[8];
    float lp[8];
    #pragma unroll
    for (int h = 0; h < 8; h++) { O[h] = (f4){0.f,0.f,0.f,0.f}; lp[h] = 0.f; }

    const __fp16* kbase = Kh + (size_t)(wave*16)*1024 + lane*16;
    const __fp16* vbase = Vh + (size_t)(wave*16)*1024 + lane*16;

    U32B ka = ld32(kbase), va = ld32(vbase);
    U32B kb, vb;

#define ATTN_QBLK(QF, HOFF, KF, VF)                                               \
    _Pragma("unroll")                                                             \
    for (int h = 0; h < 4; h++) {                                                 \
        const f4 z = {0.f, 0.f, 0.f, 0.f};                                        \
        f4 S0 = __builtin_amdgcn_mfma_f32_16x16x16f16(KF.f[0], QF.f[h], z, 0,0,0);\
        f4 S1 = __builtin_amdgcn_mfma_f32_16x16x16f16(KF.f[1], QF.f[h], z, 0,0,0);\
        f4 S2 = __builtin_amdgcn_mfma_f32_16x16x16f16(KF.f[2], QF.f[h], z, 0,0,0);\
        f4 S3 = __builtin_amdgcn_mfma_f32_16x16x16f16(KF.f[3], QF.f[h], z, 0,0,0);\
        float p0, p1, p2, p3; h2 lo, hi; h4 P; float lacc = 0.f;                  \
        p0 = __builtin_amdgcn_exp2f(S0.x); p1 = __builtin_amdgcn_exp2f(S0.y);     \
        p2 = __builtin_amdgcn_exp2f(S0.z); p3 = __builtin_amdgcn_exp2f(S0.w);     \
        lacc += p0 + p1 + p2 + p3;                                                \
        lo = __builtin_amdgcn_cvt_pkrtz(p0, p1);                                  \
        hi = __builtin_amdgcn_cvt_pkrtz(p2, p3);                                  \
        P = (h4){lo.x, lo.y, hi.x, hi.y};                                         \
        O[HOFF+h] = __builtin_amdgcn_mfma_f32_16x16x16f16(VF.f[0], P, O[HOFF+h], 0,0,0);\
        p0 = __builtin_amdgcn_exp2f(S1.x); p1 = __builtin_amdgcn_exp2f(S1.y);     \
        p2 = __builtin_amdgcn_exp2f(S1.z); p3 = __builtin_amdgcn_exp2f(S1.w);     \
        lacc += p0 + p1 + p2 + p3;                                                \
        lo = __builtin_amdgcn_cvt_pkrtz(p0, p1);                                  \
        hi = __builtin_amdgcn_cvt_pkrtz(p2, p3);                                  \
        P = (h4){lo.x, lo.y, hi.x, hi.y};                                         \
        O[HOFF+h] = __builtin_amdgcn_mfma_f32_16x16x16f16(VF.f[1], P, O[HOFF+h], 0,0,0);\
        p0 = __builtin_amdgcn_exp2f(S2.x); p1 = __builtin_amdgcn_exp2f(S2.y);     \
        p2 = __builtin_amdgcn_exp2f(S2.z); p3 = __builtin_amdgcn_exp2f(S2.w);     \
        lacc += p0 + p1 + p2 + p3;                                                \
        lo = __builtin_amdgcn_cvt_pkrtz(p0, p1);                                  \
        hi = __builtin_amdgcn_cvt_pkrtz(p2, p3);                                  \
        P = (h4){lo.x, lo.y, hi.x, hi.y};                                         \
        O[HOFF+h] = __builtin_amdgcn_mfma_f32_16x16x16f16(VF.f[2], P, O[HOFF+h], 0,0,0);\
        p0 = __builtin_amdgcn_exp2f(S3.x); p1 = __builtin_amdgcn_exp2f(S3.y);     \
        p2 = __builtin_amdgcn_exp2f(S3.z); p3 = __builtin_amdgcn_exp2f(S3.w);     \
        lacc += p0 + p1 + p2 + p3;                                                \
        lo = __builtin_amdgcn_cvt_pkrtz(p0, p1);                                  \
        hi = __builtin_amdgcn_cvt_pkrtz(p2, p3);                                  \
        P = (h4){lo.x, lo.y, hi.x, hi.y};                                         \
        O[HOFF+h] = __builtin_amdgcn_mfma_f32_16x16x16f16(VF.f[3], P, O[HOFF+h], 0,0,0);\
        lp[HOFF+h] += lacc;                                                       \
    }

#define ATTN_CHUNK(KF, VF)      \
    ATTN_QBLK(qa, 0, KF, VF)    \
    ATTN_QBLK(qb, 4, KF, VF)

    for (int it = 0; it < 16; it += 2) {
        kb = ld32(kbase + (size_t)(it + 1)*1024);
        vb = ld32(vbase + (size_t)(it + 1)*1024);
        ATTN_CHUNK(ka, va)
        {
            const int c2 = (it + 2 < 16) ? it + 2 : 15;   // redundant tail load, harmless
            ka = ld32(kbase + (size_t)c2*1024);
            va = ld32(vbase + (size_t)c2*1024);
        }
        ATTN_CHUNK(kb, vb)
    }
#undef ATTN_CHUNK
#undef ATTN_QBLK

    #pragma unroll
    for (int h = 0; h < 8; h++) {
        Osm[wave][h][lane] = O[h];
        Lsm[wave][h][lane] = lp[h];
    }
    __syncthreads();

    // wave w finalizes q-subblocks 2w and 2w+1; lane owns q = q0+hh2*16+lq, d = g*4..+3
    const int b = head >> 2, hh = head & 3;
    #pragma unroll
    for (int e = 0; e < 2; e++) {
        const int hh2 = wave*2 + e;
        f4 Os = Osm[0][hh2][lane];
        Os += Osm[1][hh2][lane];
        Os += Osm[2][hh2][lane];
        Os += Osm[3][hh2][lane];
        float L = 0.f;
        #pragma unroll
        for (int ks = 0; ks < 4; ks++)
            #pragma unroll
            for (int gg = 0; gg < 4; gg++)
                L += Lsm[ks][hh2][gg*16 + lq];
        const float rinv = 1.f / L;
        h2 lo = __builtin_amdgcn_cvt_pkrtz(Os.x*rinv, Os.y*rinv);
        h2 hi = __builtin_amdgcn_cvt_pkrtz(Os.z*rinv, Os.w*rinv);
        h4 pk = (h4){lo.x, lo.y, hi.x, hi.y};
        const size_t rblk = ((size_t)b*TT + q0) / 16 + hh2;
        *(h4*)(yh + rblk*1024 + lane*16 + hh*4) = pk;
    }
}

// ---------------- Kernel C: out = y @ w_proj^T + b_proj, swizzled y frags (identical to R11) ----------------
__global__ __launch_bounds__(256) void proj_kernel(const __fp16* __restrict__ yh,
        const float* __restrict__ w, const float* __restrict__ bias,
        float* __restrict__ out) {
    const int t = threadIdx.x;
    const int wave = t >> 6, lane = t & 63;
    const int lq = lane & 15, g = lane >> 4;
    const int r0 = blockIdx.x*16;
    const int o0 = wave*16;

    U32B yb = ld32(yh + (size_t)blockIdx.x*1024 + lane*16);

    float4 bv = *(const float4*)(bias + o0 + g*4);
    f4 acc = {bv.x, bv.y, bv.z, bv.w};
    #pragma unroll
    for (int s = 0; s < 4; s++) {
        float4 wv = *(const float4*)(w + (size_t)(o0 + lq)*CC + s*16 + g*4);
        h2 lo = __builtin_amdgcn_cvt_pkrtz(wv.x, wv.y);
        h2 hi = __builtin_amdgcn_cvt_pkrtz(wv.z, wv.w);
        h4 af = (h4){lo.x, lo.y, hi.x, hi.y};
        acc = __builtin_amdgcn_mfma_f32_16x16x16f16(af, yb.f[s], acc, 0, 0, 0);
    }
    *(float4*)(out + (size_t)(r0 + lq)*CC + o0 + g*4) = (float4){acc.x, acc.y, acc.z, acc.w};
}

extern "C" void kernel_launch(void* const* d_in, const int* in_sizes, int n_in,
                              void* d_out, int out_size, void* d_ws, size_t ws_size,
                              hipStream_t stream) {
    const float* x      = (const float*)d_in[0];
    const float* w_attn = (const float*)d_in[1];
    const float* b_attn = (const float*)d_in[2];
    const float* w_proj = (const float*)d_in[3];
    const float* b_proj = (const float*)d_in[4];
    float* out = (float*)d_out;

    const size_t headsz = (size_t)BB*HH*TT*DH;
    __fp16* Q   = (__fp16*)d_ws;
    __fp16* K   = Q + headsz;
    __fp16* VT  = K + headsz;
    __fp16* yh  = VT + headsz;

    qkv_kernel<<<NROW/16, 256, 0, stream>>>(x, w_attn, b_attn, Q, K, VT);
    attn_kernel<<<BB*HH*(TT/128), 256, 0, stream>>>(Q, K, VT, yh);
    proj_kernel<<<NROW/16, 256, 0, stream>>>(yh, w_proj, b_proj, out);
}